// Round 8
// baseline (232.660 us; speedup 1.0000x reference)
//
#include <hip/hip_runtime.h>

// VectorQuantizer: x [8,16,256,256] fp32 -> N=32768 rows, D=256; codebook K=4096 x 256.
// d_out flat (read back as float32):
//   [0 .. 8388608)   z_q_st  (= codebook[argmin])
//   [8388608]        loss = 1.25 * mean((z_q - x)^2)
//   [8388609 ..)     encoding indices, written as float values
//
// R17 pipeline:
//   convertB: codebook fp32 -> bf16, MFMA-swizzled (1 KB frag blocks). Init fused.
//   screen:   128 rows/block, 512 threads, 256 blocks; 2 MB B/CU; (512,2) bounds.
//             R17 changes (both use currently-FREE resources):
//             (1) ah[0..2] in REGISTERS (96 VGPR): occupancy is LDS-pinned at
//                 2 waves/SIMD and cap is 256 regs - the headroom costs nothing.
//                 Halves in-loop LDS reads (16->8/ct) + lgkmcnt chains. R14's
//                 intent, now with correct bounds (R14 spilled at implicit 128
//                 cap; R15/R16 sat at 128 of 256). Spill tell = WRITE_SIZE jump.
//             (2) s_setprio(1) around the MFMA kc-loop [T5]: barrier-free waves
//                 drift out of phase (MFMA vs key-chain roles) - m191's positive
//                 regime. Keeps matrix pipe fed during the other wave's VALU.
//             Rolling refill + 0x38F VMEM pin kept (R16: neutral, not harmful).
//             med3 top-3, ct-phase stagger kept.
//   fix:      candfix + ovf + finalize fused (last-block ticket, threadfence).
// Error budget unchanged (absmax 0 in R6..R16): screen 5sigma ~4.4e-5,
// np bin <= 3.05e-5, EPSQ=40 (1.46e-4); column-saturation (4-in-64-col) -> ovf.
typedef __attribute__((ext_vector_type(8))) short bf16x8;
typedef __attribute__((ext_vector_type(4))) float f32x4;

#define DIMD 256
#define KCODES 4096
#define NROWS 32768
#define OUT_LOSS 8388608
#define OUT_IDX  8388609
#define MAXC 8
#define EPSQ 40u              // candidate window in qsteps (40*3.66e-6 = 1.46e-4)
#define QSCALE 273066.67f     // 65536/0.24 : qdist = (dist + 0.12) * QSCALE
#define QBIAS  0.12f

struct CandEntry { int row; int cnt; int codes[MAXC]; };   // 40 B

// ws layout (bytes): loss f32 @0 | wcount i32 @32 | ovfcount i32 @36 | done i32 @40 |
// clist @4096 (16384 x 40 B) | ovflist @659456 (8192 i32) | Bsw @1MB (2 MB)
#define WS_CLIST 4096u
#define CCAP     16384
#define WS_OVF   659456u
#define OVFCAP   8192
#define WS_BSW   (1024u*1024u)
#define WS_END   (WS_BSW + (unsigned)KCODES*DIMD*2u)   // 3,145,728

// screen LDS (bytes): [0,98816) keys (128*193 u32) UNION A-frags (65536 B)
// [98816,99328) widx (128 i32) | [99328,99360) wpart (8 f32)
#define SROWS      128
#define SMEM_WIDX  98816
#define SMEM_WPART 99328
#define SMEM_BYTES 99360

__device__ __forceinline__ unsigned short bf16_rne(float f) {
    unsigned u = __float_as_uint(f);
    u += 0x7FFFu + ((u >> 16) & 1u);
    return (unsigned short)(u >> 16);
}

// median of 3 u32 (single VALU op). Sorted top-3 insert == min + med3 + med3.
__device__ __forceinline__ unsigned med3u(unsigned a, unsigned b, unsigned c) {
    unsigned d;
    asm("v_med3_u32 %0, %1, %2, %3" : "=v"(d) : "v"(a), "v"(b), "v"(c));
    return d;
}

__global__ void init_kernel(float* __restrict__ loss_acc, int* __restrict__ wcount,
                            int* __restrict__ ovfcount) {
    if (threadIdx.x == 0) { loss_acc[0] = 0.0f; wcount[0] = 0; ovfcount[0] = 0; }
}

// Swizzle: unit u -> (code c, k-chunk kc, laneq). Src: cb[c*256 + kc*32 + laneq*8 ..+8].
// Dst frag block: g = c>>4, lanem = c&15 -> ((g*8 + kc)*64 + lanem*4 + laneq) * 8 shorts.
__global__ __launch_bounds__(256) void convertB_kernel(const float* __restrict__ src,
                                                       unsigned short* __restrict__ bsw,
                                                       float* __restrict__ loss_acc,
                                                       int* __restrict__ wcount,
                                                       int* __restrict__ ovfcount,
                                                       int* __restrict__ done) {
    if (blockIdx.x == 0 && threadIdx.x == 0) {
        loss_acc[0] = 0.0f; wcount[0] = 0; ovfcount[0] = 0; done[0] = 0;
    }
    const unsigned u = blockIdx.x * 256 + threadIdx.x;   // 0 .. 131071
    const int laneq = u & 3;
    const int kc    = (u >> 2) & 7;
    const int c     = u >> 5;
    const float4 f0 = *(const float4*)(src + (size_t)c * DIMD + kc * 32 + laneq * 8);
    const float4 f1 = *(const float4*)(src + (size_t)c * DIMD + kc * 32 + laneq * 8 + 4);
    ushort4 h0, h1;
    h0.x = bf16_rne(f0.x); h0.y = bf16_rne(f0.y); h0.z = bf16_rne(f0.z); h0.w = bf16_rne(f0.w);
    h1.x = bf16_rne(f1.x); h1.y = bf16_rne(f1.y); h1.z = bf16_rne(f1.z); h1.w = bf16_rne(f1.w);
    const int g = c >> 4, lanem = c & 15;
    unsigned short* dst = bsw + ((size_t)((g * 8 + kc) * 64 + lanem * 4 + laneq)) * 8;
    *(ushort4*)(dst) = h0;
    *(ushort4*)(dst + 4) = h1;
}

__global__ __launch_bounds__(512, 2) void vq_screen_kernel(
        const unsigned short* __restrict__ Bsw,
        const float* __restrict__ x, const float* __restrict__ cb,
        float* __restrict__ out, float* __restrict__ loss_acc,
        int* __restrict__ wcount, CandEntry* __restrict__ clist,
        int* __restrict__ ovfcount, int* __restrict__ ovflist) {
    __shared__ __align__(16) char smem[SMEM_BYTES];
    unsigned short* Asw = (unsigned short*)smem;          // during main loop
    unsigned* keys = (unsigned*)smem;                     // after main loop (union)
    int*   widx  = (int*)(smem + SMEM_WIDX);
    float* wpart = (float*)(smem + SMEM_WPART);

    const int tid   = threadIdx.x;
    const int wv    = tid >> 6;          // 0..7
    const int rh    = wv >> 2;           // row half (0: rows 0-63, 1: rows 64-127)
    const int w4    = wv & 3;            // code quarter within each 128-tile
    const int lane  = tid & 63;
    const int lanem = lane & 15;
    const int laneq = lane >> 4;
    const int rb    = blockIdx.x * SROWS;
    const int phase = blockIdx.x & 31;   // ct stagger: spread L2 sweep across blocks

    // Cooperative A staging: 128 rows fp32 -> bf16 MFMA frags in LDS, ONCE per block.
    // Frag (i,kc) slot = lane L (row i*16+(L&15), k [kc*32+(L>>4)*8..+8)):
    // byte offset ((i*8+kc)*64 + L)*16. [R12-proven layout, i extended to 0..7]
    #pragma unroll
    for (int q = 0; q < 8; ++q) {
        const unsigned u = q * 512 + tid;     // 0..4095: (rr, kc, lq)
        const int lq = u & 3;
        const int kc = (u >> 2) & 7;
        const int rr = u >> 5;                // 0..127
        const float* srcp = x + (size_t)(rb + rr) * DIMD + kc * 32 + lq * 8;
        const float4 f0 = *(const float4*)(srcp);
        const float4 f1 = *(const float4*)(srcp + 4);
        bf16x8 v;
        v[0] = (short)bf16_rne(f0.x); v[1] = (short)bf16_rne(f0.y);
        v[2] = (short)bf16_rne(f0.z); v[3] = (short)bf16_rne(f0.w);
        v[4] = (short)bf16_rne(f1.x); v[5] = (short)bf16_rne(f1.y);
        v[6] = (short)bf16_rne(f1.z); v[7] = (short)bf16_rne(f1.w);
        const int i = rr >> 4, lm = rr & 15;
        *(bf16x8*)(Asw + ((size_t)((i * 8 + kc) * 64 + lq * 16 + lm)) * 8) = v;
    }
    __syncthreads();

    // This wave owns row-frags rf = rh*4 + 0..3. R17: hold 3 in regs (96 VGPR) -
    // occupancy is LDS-pinned at 2 waves/SIMD, cap 256 via (512,2), so the
    // headroom is free. a3k stays in LDS (margin vs spill: ~238/256 used).
    bf16x8 ah[3][8];
    #pragma unroll
    for (int i = 0; i < 3; ++i)
        #pragma unroll
        for (int kc = 0; kc < 8; ++kc)
            ah[i][kc] = *(const bf16x8*)(Asw + (size_t)(((rh * 4 + i) * 8 + kc) * 64 + lane) * 8);

    // Per-lane/slot TOP-3 packed keys; 16 slots = 4 row-blocks x 4 regs.
    unsigned b1[16], b2[16], b3[16];
    #pragma unroll
    for (int s = 0; s < 16; ++s) { b1[s] = 0xFFFFFFFFu; b2[s] = 0xFFFFFFFFu; b3[s] = 0xFFFFFFFFu; }

    const int loff = (lanem * 4 + laneq) * 8;   // lane offset inside 1 KB Bsw frag block

#define LOADH(dst, ctv, jv)                                                       \
    do {                                                                          \
        const int g_ = (ctv) * 8 + w4 * 2 + (jv);                                 \
        _Pragma("unroll")                                                         \
        for (int kc_ = 0; kc_ < 8; ++kc_)                                         \
            dst[kc_] = *(const bf16x8*)(Bsw + (size_t)(g_ * 8 + kc_) * 512 + loff); \
    } while (0)

    bf16x8 bA[8], bB[8];
    LOADH(bA, phase, 0);
    LOADH(bB, phase, 1);

    for (int ct = 0; ct < KCODES / 128; ++ct) {
        const int ctp = (ct + phase) & 31;
        const int ctn = (ctp + 1) & 31;      // next iter's tile (wraps: dead loads)
        f32x4 acc0[4], acc1[4];
        #pragma unroll
        for (int i = 0; i < 4; ++i) {
            acc0[i] = (f32x4){0.f, 0.f, 0.f, 0.f};
            acc1[i] = (f32x4){0.f, 0.f, 0.f, 0.f};
        }

        // Next-tile frag-group bases for the rolling refill.
        const int gA = ctn * 8 + w4 * 2 + 0;
        const int gB = ctn * 8 + w4 * 2 + 1;

        // T5: waves drift out of phase (no barrier) -> role diversity; favor
        // the wave that is in its MFMA cluster so the matrix pipe stays fed.
        __builtin_amdgcn_s_setprio(1);
        #pragma unroll
        for (int kc = 0; kc < 8; ++kc) {
            const bf16x8 a3k = *(const bf16x8*)(Asw + (size_t)(((rh * 4 + 3) * 8 + kc) * 64 + lane) * 8);
            acc0[0] = __builtin_amdgcn_mfma_f32_16x16x32_bf16(ah[0][kc], bA[kc], acc0[0], 0, 0, 0);
            acc1[0] = __builtin_amdgcn_mfma_f32_16x16x32_bf16(ah[0][kc], bB[kc], acc1[0], 0, 0, 0);
            acc0[1] = __builtin_amdgcn_mfma_f32_16x16x32_bf16(ah[1][kc], bA[kc], acc0[1], 0, 0, 0);
            acc1[1] = __builtin_amdgcn_mfma_f32_16x16x32_bf16(ah[1][kc], bB[kc], acc1[1], 0, 0, 0);
            acc0[2] = __builtin_amdgcn_mfma_f32_16x16x32_bf16(ah[2][kc], bA[kc], acc0[2], 0, 0, 0);
            acc1[2] = __builtin_amdgcn_mfma_f32_16x16x32_bf16(ah[2][kc], bB[kc], acc1[2], 0, 0, 0);
            acc0[3] = __builtin_amdgcn_mfma_f32_16x16x32_bf16(a3k, bA[kc], acc0[3], 0, 0, 0);
            acc1[3] = __builtin_amdgcn_mfma_f32_16x16x32_bf16(a3k, bB[kc], acc1[3], 0, 0, 0);
            // Rolling refill: bA[kc]/bB[kc] are dead after the MFMAs above.
            bA[kc] = *(const bf16x8*)(Bsw + (size_t)(gA * 8 + kc) * 512 + loff);
            bB[kc] = *(const bf16x8*)(Bsw + (size_t)(gB * 8 + kc) * 512 + loff);
            // Pin VMEM issue points only; ALU/VALU/SALU/MFMA/DS free to cross.
            __builtin_amdgcn_sched_barrier(0x38F);
        }
        __builtin_amdgcn_s_setprio(0);

        // key = qdist<<12 | code; top-3 insert = min + med3 + med3 (identical result).
        {
            const unsigned code = (unsigned)(ctp * 128 + w4 * 32 + lanem);
            #pragma unroll
            for (int i = 0; i < 4; ++i)
                #pragma unroll
                for (int r = 0; r < 4; ++r) {
                    const int s = i * 4 + r;
                    const float dist = fmaf(acc0[i][r], -2.0f * QSCALE, QBIAS * QSCALE);
                    const unsigned k = ((unsigned)dist << 12) | code;
                    const unsigned nb1 = min(b1[s], k);
                    const unsigned nb2 = med3u(b1[s], b2[s], k);
                    const unsigned nb3 = med3u(b2[s], b3[s], k);
                    b1[s] = nb1; b2[s] = nb2; b3[s] = nb3;
                }
        }
        {
            const unsigned code = (unsigned)(ctp * 128 + w4 * 32 + 16 + lanem);
            #pragma unroll
            for (int i = 0; i < 4; ++i)
                #pragma unroll
                for (int r = 0; r < 4; ++r) {
                    const int s = i * 4 + r;
                    const float dist = fmaf(acc1[i][r], -2.0f * QSCALE, QBIAS * QSCALE);
                    const unsigned k = ((unsigned)dist << 12) | code;
                    const unsigned nb1 = min(b1[s], k);
                    const unsigned nb2 = med3u(b1[s], b2[s], k);
                    const unsigned nb3 = med3u(b2[s], b3[s], k);
                    b1[s] = nb1; b2[s] = nb2; b3[s] = nb3;
                }
        }
    }
#undef LOADH

    __syncthreads();   // Asw dead from here; keys region reuses the same LDS.

    // Merge via LDS. Column src = w4*16 + lanem (0..63); rows rh*64 + 0..63.
    {
        const int src = w4 * 16 + lanem;
        #pragma unroll
        for (int i = 0; i < 4; ++i)
            #pragma unroll
            for (int r = 0; r < 4; ++r) {
                const int s = i * 4 + r;
                const int rr = rh * 64 + i * 16 + laneq * 4 + r;   // row within block
                keys[rr * 193 + src * 3 + 0] = b1[s];
                keys[rr * 193 + src * 3 + 1] = b2[s];
                keys[rr * 193 + src * 3 + 2] = b3[s];
            }
    }
    __syncthreads();
    if (tid < SROWS) {
        const int base = tid * 193;
        unsigned kmin = 0xFFFFFFFFu;
        for (int t = 0; t < 192; ++t) kmin = min(kmin, keys[base + t]);
        const unsigned thr = (((kmin >> 12) + EPSQ) << 12) | 0xFFFu;
        int cand[MAXC]; int nc = 0; int ovf = 0;
        for (int L = 0; L < 64; ++L) {
            const unsigned v0 = keys[base + L * 3 + 0];
            if (v0 <= thr) {
                if (nc < MAXC) cand[nc] = (int)(v0 & 0xFFFu);
                ++nc;
                const unsigned v1 = keys[base + L * 3 + 1];
                if (v1 <= thr) {
                    if (nc < MAXC) cand[nc] = (int)(v1 & 0xFFFu);
                    ++nc;
                    const unsigned v2 = keys[base + L * 3 + 2];
                    if (v2 <= thr) {      // column's 4th-best unknown -> conservative
                        if (nc < MAXC) cand[nc] = (int)(v2 & 0xFFFu);
                        ++nc;
                        ovf = 1;
                    }
                }
            }
        }
        const int row = rb + tid;
        const int bi = (int)(kmin & 0xFFFu);
        widx[tid] = bi;
        out[OUT_IDX + (size_t)row] = (float)bi;
        if (ovf || nc > MAXC) {
            const int op = atomicAdd(ovfcount, 1);
            if (op < OVFCAP) ovflist[op] = row;
        } else if (nc >= 2) {
            const int pos = atomicAdd(wcount, 1);
            if (pos < CCAP) {
                CandEntry* e = &clist[pos];
                e->row = row; e->cnt = nc;
                for (int q = 0; q < nc; ++q) e->codes[q] = cand[q];
            } else {
                const int op = atomicAdd(ovfcount, 1);
                if (op < OVFCAP) ovflist[op] = row;
            }
        }
    }
    __syncthreads();

    // Gather z_q, write z_q_st = x + (z_q - x), accumulate loss partial. 128 rows.
    float lsum = 0.0f;
    const int dv = (tid & 63) * 4;
    const int rs = tid >> 6;
    const float* xblk = x + (size_t)rb * DIMD;
    float* oblk = out + (size_t)rb * DIMD;
    for (int p = 0; p < 16; ++p) {
        const int row = p * 8 + rs;
        const int wi = widx[row];
        float4 xv = *(const float4*)(xblk + (size_t)row * DIMD + dv);
        float4 cv = *(const float4*)(cb + (size_t)wi * DIMD + dv);
        const float d0 = cv.x - xv.x, d1 = cv.y - xv.y, d2 = cv.z - xv.z, d3 = cv.w - xv.w;
        float4 o;
        o.x = xv.x + d0; o.y = xv.y + d1; o.z = xv.z + d2; o.w = xv.w + d3;
        *(float4*)(oblk + (size_t)row * DIMD + dv) = o;
        lsum += d0 * d0 + d1 * d1 + d2 * d2 + d3 * d3;
    }
    #pragma unroll
    for (int off = 32; off > 0; off >>= 1) lsum += __shfl_down(lsum, off, 64);
    if ((tid & 63) == 0) wpart[tid >> 6] = lsum;
    __syncthreads();
    if (tid == 0) {
        float t = 0.0f;
        #pragma unroll
        for (int i = 0; i < 8; ++i) t += wpart[i];
        atomicAdd(loss_acc, t);
    }
}

// Fused fixup + finalize: Part 1 candfix (one wave per flagged row, np-bin metric
// over <=8 candidates [R5..R8-proven]); Part 2 ovf full-rescan (block per item);
// Part 3 last-block ticket writes out[OUT_LOSS] (threadfence + device atomics).
__global__ __launch_bounds__(256) void vq_fix_kernel(
        const float* __restrict__ x, const float* __restrict__ cb,
        float* __restrict__ out, float* __restrict__ loss_acc,
        const int* __restrict__ wcount, const CandEntry* __restrict__ clist,
        const int* __restrict__ ovfcount, const int* __restrict__ ovflist,
        int* __restrict__ done) {
    __shared__ double xd[DIMD];
    __shared__ double zred[256];
    __shared__ float  rdq[256];
    __shared__ int    ri[256];
    __shared__ float  lred[256];
    const int tid = threadIdx.x;

    // ---- Part 1: candfix ----
    {
        int count = wcount[0];
        if (count > CCAP) count = CCAP;
        const int lane = tid & 63;
        const int gw = blockIdx.x * 4 + (tid >> 6);
        const int nw = gridDim.x * 4;
        for (int it = gw; it < count; it += nw) {
            const CandEntry* e = clist + it;
            const int row = e->row;
            const int cnt = e->cnt;
            const float4 xv = *(const float4*)(x + (size_t)row * DIMD + lane * 4);
            double zs = (double)xv.x * xv.x + (double)xv.y * xv.y
                      + (double)xv.z * xv.z + (double)xv.w * xv.w;
            #pragma unroll
            for (int off = 32; off > 0; off >>= 1) zs += __shfl_xor(zs, off, 64);
            const float Zf = (float)zs;   // grid-aligned z_sq (translation-invariance)
            float bq = 3.4e38f; int bi = 0x7fffffff;
            for (int q = 0; q < cnt; ++q) {
                const int c = e->codes[q];
                const float4 cv = *(const float4*)(cb + (size_t)c * DIMD + lane * 4);
                double dp = (double)xv.x * cv.x + (double)xv.y * cv.y
                          + (double)xv.z * cv.z + (double)xv.w * cv.w;
                #pragma unroll
                for (int off = 32; off > 0; off >>= 1) dp += __shfl_xor(dp, off, 64);
                const float wv = (float)(2.0 * dp);
                const float dq = Zf - wv;             // fp32 subtract = np's bin
                if (dq < bq || (dq == bq && c < bi)) { bq = dq; bi = c; }
            }
            const int oldi = (int)out[OUT_IDX + (size_t)row];
            if (bi != oldi) {
                const float4 cn = *(const float4*)(cb + (size_t)bi * DIMD + lane * 4);
                const float4 co = *(const float4*)(cb + (size_t)oldi * DIMD + lane * 4);
                float4 o; float ls = 0.0f;
                { const float dn = cn.x - xv.x, dd = co.x - xv.x; o.x = xv.x + dn; ls += dn*dn - dd*dd; }
                { const float dn = cn.y - xv.y, dd = co.y - xv.y; o.y = xv.y + dn; ls += dn*dn - dd*dd; }
                { const float dn = cn.z - xv.z, dd = co.z - xv.z; o.z = xv.z + dn; ls += dn*dn - dd*dd; }
                { const float dn = cn.w - xv.w, dd = co.w - xv.w; o.w = xv.w + dn; ls += dn*dn - dd*dd; }
                *(float4*)(out + (size_t)row * DIMD + lane * 4) = o;
                #pragma unroll
                for (int off = 32; off > 0; off >>= 1) ls += __shfl_xor(ls, off, 64);
                if (lane == 0) {
                    atomicAdd(loss_acc, ls);
                    out[OUT_IDX + (size_t)row] = (float)bi;
                }
            }
        }
    }

    // ---- Part 2: ovf full rescan (expected ~0 items) ----
    __syncthreads();
    {
        int count = ovfcount[0];
        if (count > OVFCAP) count = OVFCAP;
        for (int item = blockIdx.x; item < count; item += gridDim.x) {
            const int row = ovflist[item];
            const double xv0 = (double)x[(size_t)row * DIMD + tid];
            xd[tid] = xv0;
            zred[tid] = xv0 * xv0;
            __syncthreads();
            for (int st = 128; st > 0; st >>= 1) {
                if (tid < st) zred[tid] += zred[tid + st];
                __syncthreads();
            }
            const float Zf = (float)zred[0];
            float bq = 3.4e38f; int bi = 0x7fffffff;
            for (int q = 0; q < 16; ++q) {
                const int c = q * 256 + tid;
                const float* cr = cb + (size_t)c * DIMD;
                double s0 = 0.0, s1 = 0.0, s2 = 0.0, s3 = 0.0;
                #pragma unroll 4
                for (int d = 0; d < DIMD; d += 16) {
                    float4 c0 = *(const float4*)(cr + d);
                    float4 c1 = *(const float4*)(cr + d + 4);
                    float4 c2 = *(const float4*)(cr + d + 8);
                    float4 c3 = *(const float4*)(cr + d + 12);
                    s0 += xd[d + 0] * (double)c0.x + xd[d + 1] * (double)c0.y
                        + xd[d + 2] * (double)c0.z + xd[d + 3] * (double)c0.w;
                    s1 += xd[d + 4] * (double)c1.x + xd[d + 5] * (double)c1.y
                        + xd[d + 6] * (double)c1.z + xd[d + 7] * (double)c1.w;
                    s2 += xd[d + 8] * (double)c2.x + xd[d + 9] * (double)c2.y
                        + xd[d +10] * (double)c2.z + xd[d +11] * (double)c2.w;
                    s3 += xd[d +12] * (double)c3.x + xd[d +13] * (double)c3.y
                        + xd[d +14] * (double)c3.z + xd[d +15] * (double)c3.w;
                }
                const double s = (s0 + s1) + (s2 + s3);
                const float wv = (float)(2.0 * s);
                const float dq = Zf - wv;
                if (dq < bq || (dq == bq && c < bi)) { bq = dq; bi = c; }
            }
            rdq[tid] = bq; ri[tid] = bi;
            __syncthreads();
            for (int st = 128; st > 0; st >>= 1) {
                if (tid < st) {
                    const float oq = rdq[tid + st]; const int oi = ri[tid + st];
                    if (oq < rdq[tid] || (oq == rdq[tid] && oi < ri[tid])) {
                        rdq[tid] = oq; ri[tid] = oi;
                    }
                }
                __syncthreads();
            }
            const int newi = ri[0];
            const int oldi = (int)out[OUT_IDX + (size_t)row];
            if (newi != oldi) {
                const float xv = x[(size_t)row * DIMD + tid];
                const float co = cb[(size_t)oldi * DIMD + tid];
                const float cn = cb[(size_t)newi * DIMD + tid];
                const float dold = co - xv, dnew = cn - xv;
                out[(size_t)row * DIMD + tid] = xv + dnew;
                lred[tid] = dnew * dnew - dold * dold;
            } else {
                lred[tid] = 0.0f;
            }
            __syncthreads();
            for (int st = 128; st > 0; st >>= 1) {
                if (tid < st) lred[tid] += lred[tid + st];
                __syncthreads();
            }
            if (tid == 0 && newi != oldi) {
                atomicAdd(loss_acc, lred[0]);
                out[OUT_IDX + (size_t)row] = (float)newi;
            }
            __syncthreads();
        }
    }

    // ---- Part 3: fused finalize (last-block ticket) ----
    __syncthreads();
    if (tid == 0) {
        __threadfence();                                   // publish this block's adds
        const int t = atomicAdd(done, 1);
        if (t == (int)gridDim.x - 1) {
            __threadfence();                               // acquire all blocks' adds
            out[OUT_LOSS] = 1.25f * (loss_acc[0] / 8388608.0f);
        }
    }
}

// Standalone ovf kernel kept for the fallback fp32 path.
__global__ __launch_bounds__(256) void vq_ovf_kernel(
        const float* __restrict__ x, const float* __restrict__ cb,
        float* __restrict__ out, float* __restrict__ loss_acc,
        const int* __restrict__ ovfcount, const int* __restrict__ ovflist) {
    __shared__ double xd[DIMD];
    __shared__ double zred[256];
    __shared__ float  rdq[256];
    __shared__ int    ri[256];
    __shared__ float  lred[256];
    const int tid = threadIdx.x;
    int count = ovfcount[0];
    if (count > OVFCAP) count = OVFCAP;
    for (int item = blockIdx.x; item < count; item += gridDim.x) {
        const int row = ovflist[item];
        const double xv0 = (double)x[(size_t)row * DIMD + tid];
        xd[tid] = xv0;
        zred[tid] = xv0 * xv0;
        __syncthreads();
        for (int st = 128; st > 0; st >>= 1) {
            if (tid < st) zred[tid] += zred[tid + st];
            __syncthreads();
        }
        const float Zf = (float)zred[0];
        float bq = 3.4e38f; int bi = 0x7fffffff;
        for (int q = 0; q < 16; ++q) {
            const int c = q * 256 + tid;
            const float* cr = cb + (size_t)c * DIMD;
            double s0 = 0.0, s1 = 0.0, s2 = 0.0, s3 = 0.0;
            #pragma unroll 4
            for (int d = 0; d < DIMD; d += 16) {
                float4 c0 = *(const float4*)(cr + d);
                float4 c1 = *(const float4*)(cr + d + 4);
                float4 c2 = *(const float4*)(cr + d + 8);
                float4 c3 = *(const float4*)(cr + d + 12);
                s0 += xd[d + 0] * (double)c0.x + xd[d + 1] * (double)c0.y
                    + xd[d + 2] * (double)c0.z + xd[d + 3] * (double)c0.w;
                s1 += xd[d + 4] * (double)c1.x + xd[d + 5] * (double)c1.y
                    + xd[d + 6] * (double)c1.z + xd[d + 7] * (double)c1.w;
                s2 += xd[d + 8] * (double)c2.x + xd[d + 9] * (double)c2.y
                    + xd[d +10] * (double)c2.z + xd[d +11] * (double)c2.w;
                s3 += xd[d +12] * (double)c3.x + xd[d +13] * (double)c3.y
                    + xd[d +14] * (double)c3.z + xd[d +15] * (double)c3.w;
            }
            const double s = (s0 + s1) + (s2 + s3);
            const float wv = (float)(2.0 * s);
            const float dq = Zf - wv;
            if (dq < bq || (dq == bq && c < bi)) { bq = dq; bi = c; }
        }
        rdq[tid] = bq; ri[tid] = bi;
        __syncthreads();
        for (int st = 128; st > 0; st >>= 1) {
            if (tid < st) {
                const float oq = rdq[tid + st]; const int oi = ri[tid + st];
                if (oq < rdq[tid] || (oq == rdq[tid] && oi < ri[tid])) {
                    rdq[tid] = oq; ri[tid] = oi;
                }
            }
            __syncthreads();
        }
        const int newi = ri[0];
        const int oldi = (int)out[OUT_IDX + (size_t)row];
        if (newi != oldi) {
            const float xv = x[(size_t)row * DIMD + tid];
            const float co = cb[(size_t)oldi * DIMD + tid];
            const float cn = cb[(size_t)newi * DIMD + tid];
            const float dold = co - xv, dnew = cn - xv;
            out[(size_t)row * DIMD + tid] = xv + dnew;
            lred[tid] = dnew * dnew - dold * dold;
        } else {
            lred[tid] = 0.0f;
        }
        __syncthreads();
        for (int st = 128; st > 0; st >>= 1) {
            if (tid < st) lred[tid] += lred[tid + st];
            __syncthreads();
        }
        if (tid == 0 && newi != oldi) {
            atomicAdd(loss_acc, lred[0]);
            out[OUT_IDX + (size_t)row] = (float)newi;
        }
        __syncthreads();
    }
}

__global__ void finalize_kernel(const float* __restrict__ loss_acc, float* __restrict__ out) {
    if (threadIdx.x == 0 && blockIdx.x == 0)
        out[OUT_LOSS] = 1.25f * (loss_acc[0] / 8388608.0f);
}

// ===== fallback fp32 path (R3-proven) for small ws_size =====
#define MT 128
#define DK 32
#define LSTR 130
#define FLAG_EPS_F32 3.6e-5f
__global__ __launch_bounds__(256) void vq_main_fp32_kernel(const float* __restrict__ x,
                                                           const float* __restrict__ cb,
                                                           float* __restrict__ out,
                                                           float* __restrict__ loss_acc,
                                                           int* __restrict__ wcount,
                                                           int* __restrict__ wlist,
                                                           int wcap) {
    __shared__ float As[DK * LSTR];
    __shared__ float Bs[DK * LSTR];
    __shared__ float red_d[MT * 17];
    __shared__ float red_2[MT * 17];
    __shared__ int   red_i[MT * 17];
    __shared__ int   widx[MT];
    __shared__ float wpart[4];
    const int tid = threadIdx.x;
    const int tx = tid & 15;
    const int ty = tid >> 4;
    const float* xblk = x + (size_t)blockIdx.x * MT * DIMD;
    float b1[8], b2[8]; int i1[8];
    #pragma unroll
    for (int i = 0; i < 8; ++i) { b1[i] = 3.4e38f; b2[i] = 3.4e38f; i1[i] = 0; }
    const int sr = tid >> 3;
    const int sd = (tid & 7) * 4;
    for (int kt = 0; kt < KCODES; kt += 128) {
        float acc[8][8];
        #pragma unroll
        for (int i = 0; i < 8; ++i)
            #pragma unroll
            for (int j = 0; j < 8; ++j) acc[i][j] = 0.0f;
        const float* bblk = cb + (size_t)kt * DIMD;
        for (int dc = 0; dc < DIMD; dc += DK) {
            __syncthreads();
            #pragma unroll
            for (int p = 0; p < 4; ++p) {
                const int r = p * 32 + sr;
                float4 va = *(const float4*)(xblk + (size_t)r * DIMD + dc + sd);
                float4 vb = *(const float4*)(bblk + (size_t)r * DIMD + dc + sd);
                As[(sd + 0) * LSTR + r] = va.x; As[(sd + 1) * LSTR + r] = va.y;
                As[(sd + 2) * LSTR + r] = va.z; As[(sd + 3) * LSTR + r] = va.w;
                Bs[(sd + 0) * LSTR + r] = vb.x; Bs[(sd + 1) * LSTR + r] = vb.y;
                Bs[(sd + 2) * LSTR + r] = vb.z; Bs[(sd + 3) * LSTR + r] = vb.w;
            }
            __syncthreads();
            #pragma unroll 4
            for (int d = 0; d < DK; ++d) {
                const float2* ap = (const float2*)&As[d * LSTR + ty * 8];
                const float2* bp = (const float2*)&Bs[d * LSTR + tx * 8];
                float2 a0 = ap[0], a1 = ap[1], a2 = ap[2], a3 = ap[3];
                float2 c0 = bp[0], c1 = bp[1], c2 = bp[2], c3 = bp[3];
                float a[8] = {a0.x, a0.y, a1.x, a1.y, a2.x, a2.y, a3.x, a3.y};
                float b[8] = {c0.x, c0.y, c1.x, c1.y, c2.x, c2.y, c3.x, c3.y};
                #pragma unroll
                for (int i = 0; i < 8; ++i)
                    #pragma unroll
                    for (int j = 0; j < 8; ++j)
                        acc[i][j] += a[i] * b[j];
            }
        }
        #pragma unroll
        for (int j = 0; j < 8; ++j) {
            const int code = kt + tx * 8 + j;
            #pragma unroll
            for (int i = 0; i < 8; ++i) {
                const float dist = -(acc[i][j] + acc[i][j]);
                if (dist < b1[i]) { b2[i] = b1[i]; b1[i] = dist; i1[i] = code; }
                else if (dist < b2[i]) b2[i] = dist;
            }
        }
    }
    __syncthreads();
    #pragma unroll
    for (int i = 0; i < 8; ++i) {
        red_d[(ty * 8 + i) * 17 + tx] = b1[i];
        red_2[(ty * 8 + i) * 17 + tx] = b2[i];
        red_i[(ty * 8 + i) * 17 + tx] = i1[i];
    }
    __syncthreads();
    if (tid < MT) {
        float bd = red_d[tid * 17];
        float s2 = red_2[tid * 17];
        int   bi = red_i[tid * 17];
        #pragma unroll
        for (int t = 1; t < 16; ++t) {
            const float d1 = red_d[tid * 17 + t];
            const float d2 = red_2[tid * 17 + t];
            const int   ii = red_i[tid * 17 + t];
            if (d1 < bd || (d1 == bd && ii < bi)) { s2 = fminf(bd, d2); bd = d1; bi = ii; }
            else s2 = fminf(s2, d1);
        }
        const int row = blockIdx.x * MT + tid;
        widx[tid] = bi;
        out[OUT_IDX + (size_t)row] = (float)bi;
        if (s2 - bd <= FLAG_EPS_F32) {
            const int pos = atomicAdd(wcount, 1);
            if (pos < wcap) wlist[pos] = row;
        }
    }
    __syncthreads();
    float lsum = 0.0f;
    const int dv = (tid & 63) * 4;
    const int rs = tid >> 6;
    float* oblk = out + (size_t)blockIdx.x * MT * DIMD;
    for (int p = 0; p < 32; ++p) {
        const int row = p * 4 + rs;
        const int wi = widx[row];
        float4 xv = *(const float4*)(xblk + (size_t)row * DIMD + dv);
        float4 cv = *(const float4*)(cb + (size_t)wi * DIMD + dv);
        const float d0 = cv.x - xv.x, d1 = cv.y - xv.y, d2 = cv.z - xv.z, d3 = cv.w - xv.w;
        float4 o;
        o.x = xv.x + d0; o.y = xv.y + d1; o.z = xv.z + d2; o.w = xv.w + d3;
        *(float4*)(oblk + (size_t)row * DIMD + dv) = o;
        lsum += d0 * d0 + d1 * d1 + d2 * d2 + d3 * d3;
    }
    #pragma unroll
    for (int off = 32; off > 0; off >>= 1) lsum += __shfl_down(lsum, off, 64);
    if ((tid & 63) == 0) wpart[tid >> 6] = lsum;
    __syncthreads();
    if (tid == 0) atomicAdd(loss_acc, wpart[0] + wpart[1] + wpart[2] + wpart[3]);
}

extern "C" void kernel_launch(void* const* d_in, const int* in_sizes, int n_in,
                              void* d_out, int out_size, void* d_ws, size_t ws_size,
                              hipStream_t stream) {
    const float* x  = (const float*)d_in[0];
    const float* cb = (const float*)d_in[1];
    float* out = (float*)d_out;
    float* loss_acc = (float*)d_ws;
    int*   wcount   = (int*)((char*)d_ws + 32);
    int*   ovfcount = (int*)((char*)d_ws + 36);
    int*   done     = (int*)((char*)d_ws + 40);
    CandEntry* clist = (CandEntry*)((char*)d_ws + WS_CLIST);
    int*   ovflist  = (int*)((char*)d_ws + WS_OVF);

    if (ws_size >= (size_t)WS_END) {
        unsigned short* Bsw = (unsigned short*)((char*)d_ws + WS_BSW);
        convertB_kernel<<<512, 256, 0, stream>>>(cb, Bsw, loss_acc, wcount, ovfcount, done);
        vq_screen_kernel<<<256, 512, 0, stream>>>(Bsw, x, cb, out, loss_acc,
                                                  wcount, clist, ovfcount, ovflist);
        vq_fix_kernel<<<512, 256, 0, stream>>>(x, cb, out, loss_acc,
                                               wcount, clist, ovfcount, ovflist, done);
    } else {
        init_kernel<<<1, 64, 0, stream>>>(loss_acc, wcount, ovfcount);
        int* wlist = (int*)((char*)d_ws + WS_CLIST);
        int wcap = 0;
        if (ws_size > WS_CLIST + sizeof(int)) {
            size_t c = (ws_size - WS_CLIST) / sizeof(int);
            wcap = (int)(c > 32768 ? 32768 : c);
        }
        vq_main_fp32_kernel<<<256, 256, 0, stream>>>(x, cb, out, loss_acc,
                                                     wcount, wlist, wcap);
        vq_ovf_kernel<<<512, 256, 0, stream>>>(x, cb, out, loss_acc, wcount, wlist);
        finalize_kernel<<<1, 1, 0, stream>>>(loss_acc, out);
    }
}

// Round 9
// 183.283 us; speedup vs baseline: 1.2694x; 1.2694x over previous
//
#include <hip/hip_runtime.h>

// VectorQuantizer: x [8,16,256,256] fp32 -> N=32768 rows, D=256; codebook K=4096 x 256.
// d_out flat (read back as float32):
//   [0 .. 8388608)   z_q_st  (= codebook[argmin])
//   [8388608]        loss = 1.25 * mean((z_q - x)^2)
//   [8388609 ..)     encoding indices, written as float values
//
// R18 pipeline:
//   convertB: codebook fp32 -> bf16, MFMA-swizzled (1 KB frag blocks). Init fused.
//   screen:   R16 structure exactly (128 rows/block, 512 thr, 256 blocks, (512,2),
//             ah[2] in regs + a2k/a3k LDS, rolling refill + 0x38F, med3, stagger).
//             R17's ah[3]+setprio REVERTED: (512,2) did NOT lift the 128-reg cap
//             (VGPR pinned 128, WRITE 33->48MB spill, +46us) - avenue closed.
//             R18 NEW: candfix FUSED into screen. Each block already holds its
//             rows' candidates at merge time; flagged rows go to a 5KB LDS list
//             (not global clist), and after the gather phase the block's 8 waves
//             run candfix VERBATIM (double dots, np-bin fl32(Zf-fl32(2dot)),
//             (dq,idx)-lex min, same correction writes + atomicAdd deltas ->
//             same addend set, same error budget). Kills the fix launch gap +
//             clist round-trip. LDS 99.4->102.0KB, still 1 block/CU.
//   ovffin:   ovf full-rescan (expected ~0 rows) + finalize ticket.
// Error budget unchanged (absmax 0 in R6..R17): screen 5sigma ~4.4e-5,
// np bin <= 3.05e-5, EPSQ=40 (1.46e-4); column-saturation (4-in-64-col) -> ovf.
typedef __attribute__((ext_vector_type(8))) short bf16x8;
typedef __attribute__((ext_vector_type(4))) float f32x4;

#define DIMD 256
#define KCODES 4096
#define NROWS 32768
#define OUT_LOSS 8388608
#define OUT_IDX  8388609
#define MAXC 8
#define EPSQ 40u              // candidate window in qsteps (40*3.66e-6 = 1.46e-4)
#define QSCALE 273066.67f     // 65536/0.24 : qdist = (dist + 0.12) * QSCALE
#define QBIAS  0.12f

struct CandEntry { int row; int cnt; int codes[MAXC]; };   // 40 B (fallback path)

// ws layout (bytes): loss f32 @0 | wcount i32 @32 | ovfcount i32 @36 | done i32 @40 |
// clist @4096 (fallback) | ovflist @659456 (8192 i32) | Bsw @1MB (2 MB)
#define WS_CLIST 4096u
#define CCAP     16384
#define WS_OVF   659456u
#define OVFCAP   8192
#define WS_BSW   (1024u*1024u)
#define WS_END   (WS_BSW + (unsigned)KCODES*DIMD*2u)   // 3,145,728

// screen LDS (bytes): [0,98816) keys (128*193 u32) UNION A-frags (65536 B)
// widx @98816 (128 i32) | wpart @99328 (8 f32) | bcount @99360 |
// candLds @99376: 128 entries x 10 u32 (rowLocal, cnt, codes[8]) = 5120 B
#define SROWS      128
#define SMEM_WIDX  98816
#define SMEM_WPART 99328
#define SMEM_BCNT  99360
#define SMEM_CAND  99376
#define SMEM_BYTES (SMEM_CAND + 128 * 10 * 4)   // 104,496

__device__ __forceinline__ unsigned short bf16_rne(float f) {
    unsigned u = __float_as_uint(f);
    u += 0x7FFFu + ((u >> 16) & 1u);
    return (unsigned short)(u >> 16);
}

// median of 3 u32 (single VALU op). Sorted top-3 insert == min + med3 + med3.
__device__ __forceinline__ unsigned med3u(unsigned a, unsigned b, unsigned c) {
    unsigned d;
    asm("v_med3_u32 %0, %1, %2, %3" : "=v"(d) : "v"(a), "v"(b), "v"(c));
    return d;
}

__global__ void init_kernel(float* __restrict__ loss_acc, int* __restrict__ wcount,
                            int* __restrict__ ovfcount) {
    if (threadIdx.x == 0) { loss_acc[0] = 0.0f; wcount[0] = 0; ovfcount[0] = 0; }
}

// Swizzle: unit u -> (code c, k-chunk kc, laneq). Src: cb[c*256 + kc*32 + laneq*8 ..+8].
// Dst frag block: g = c>>4, lanem = c&15 -> ((g*8 + kc)*64 + lanem*4 + laneq) * 8 shorts.
__global__ __launch_bounds__(256) void convertB_kernel(const float* __restrict__ src,
                                                       unsigned short* __restrict__ bsw,
                                                       float* __restrict__ loss_acc,
                                                       int* __restrict__ wcount,
                                                       int* __restrict__ ovfcount,
                                                       int* __restrict__ done) {
    if (blockIdx.x == 0 && threadIdx.x == 0) {
        loss_acc[0] = 0.0f; wcount[0] = 0; ovfcount[0] = 0; done[0] = 0;
    }
    const unsigned u = blockIdx.x * 256 + threadIdx.x;   // 0 .. 131071
    const int laneq = u & 3;
    const int kc    = (u >> 2) & 7;
    const int c     = u >> 5;
    const float4 f0 = *(const float4*)(src + (size_t)c * DIMD + kc * 32 + laneq * 8);
    const float4 f1 = *(const float4*)(src + (size_t)c * DIMD + kc * 32 + laneq * 8 + 4);
    ushort4 h0, h1;
    h0.x = bf16_rne(f0.x); h0.y = bf16_rne(f0.y); h0.z = bf16_rne(f0.z); h0.w = bf16_rne(f0.w);
    h1.x = bf16_rne(f1.x); h1.y = bf16_rne(f1.y); h1.z = bf16_rne(f1.z); h1.w = bf16_rne(f1.w);
    const int g = c >> 4, lanem = c & 15;
    unsigned short* dst = bsw + ((size_t)((g * 8 + kc) * 64 + lanem * 4 + laneq)) * 8;
    *(ushort4*)(dst) = h0;
    *(ushort4*)(dst + 4) = h1;
}

__global__ __launch_bounds__(512, 2) void vq_screen_kernel(
        const unsigned short* __restrict__ Bsw,
        const float* __restrict__ x, const float* __restrict__ cb,
        float* __restrict__ out, float* __restrict__ loss_acc,
        int* __restrict__ ovfcount, int* __restrict__ ovflist) {
    __shared__ __align__(16) char smem[SMEM_BYTES];
    unsigned short* Asw = (unsigned short*)smem;          // during main loop
    unsigned* keys = (unsigned*)smem;                     // after main loop (union)
    int*   widx  = (int*)(smem + SMEM_WIDX);
    float* wpart = (float*)(smem + SMEM_WPART);
    int*   bcnt  = (int*)(smem + SMEM_BCNT);
    int*   candL = (int*)(smem + SMEM_CAND);

    const int tid   = threadIdx.x;
    const int wv    = tid >> 6;          // 0..7
    const int rh    = wv >> 2;           // row half (0: rows 0-63, 1: rows 64-127)
    const int w4    = wv & 3;            // code quarter within each 128-tile
    const int lane  = tid & 63;
    const int lanem = lane & 15;
    const int laneq = lane >> 4;
    const int rb    = blockIdx.x * SROWS;
    const int phase = blockIdx.x & 31;   // ct stagger: spread L2 sweep across blocks

    if (tid == 0) bcnt[0] = 0;

    // Cooperative A staging: 128 rows fp32 -> bf16 MFMA frags in LDS, ONCE per block.
    // Frag (i,kc) slot = lane L (row i*16+(L&15), k [kc*32+(L>>4)*8..+8)):
    // byte offset ((i*8+kc)*64 + L)*16. [R12-proven layout, i extended to 0..7]
    #pragma unroll
    for (int q = 0; q < 8; ++q) {
        const unsigned u = q * 512 + tid;     // 0..4095: (rr, kc, lq)
        const int lq = u & 3;
        const int kc = (u >> 2) & 7;
        const int rr = u >> 5;                // 0..127
        const float* srcp = x + (size_t)(rb + rr) * DIMD + kc * 32 + lq * 8;
        const float4 f0 = *(const float4*)(srcp);
        const float4 f1 = *(const float4*)(srcp + 4);
        bf16x8 v;
        v[0] = (short)bf16_rne(f0.x); v[1] = (short)bf16_rne(f0.y);
        v[2] = (short)bf16_rne(f0.z); v[3] = (short)bf16_rne(f0.w);
        v[4] = (short)bf16_rne(f1.x); v[5] = (short)bf16_rne(f1.y);
        v[6] = (short)bf16_rne(f1.z); v[7] = (short)bf16_rne(f1.w);
        const int i = rr >> 4, lm = rr & 15;
        *(bf16x8*)(Asw + ((size_t)((i * 8 + kc) * 64 + lq * 16 + lm)) * 8) = v;
    }
    __syncthreads();

    // This wave owns row-frags rf = rh*4 + 0..3. ah[0..1] in regs (proven 128-reg
    // fit); a2k/a3k read per-ct from LDS (separate pipe, conflict-free layout).
    bf16x8 ah[2][8];
    #pragma unroll
    for (int i = 0; i < 2; ++i)
        #pragma unroll
        for (int kc = 0; kc < 8; ++kc)
            ah[i][kc] = *(const bf16x8*)(Asw + (size_t)(((rh * 4 + i) * 8 + kc) * 64 + lane) * 8);

    // Per-lane/slot TOP-3 packed keys; 16 slots = 4 row-blocks x 4 regs.
    unsigned b1[16], b2[16], b3[16];
    #pragma unroll
    for (int s = 0; s < 16; ++s) { b1[s] = 0xFFFFFFFFu; b2[s] = 0xFFFFFFFFu; b3[s] = 0xFFFFFFFFu; }

    const int loff = (lanem * 4 + laneq) * 8;   // lane offset inside 1 KB Bsw frag block

#define LOADH(dst, ctv, jv)                                                       \
    do {                                                                          \
        const int g_ = (ctv) * 8 + w4 * 2 + (jv);                                 \
        _Pragma("unroll")                                                         \
        for (int kc_ = 0; kc_ < 8; ++kc_)                                         \
            dst[kc_] = *(const bf16x8*)(Bsw + (size_t)(g_ * 8 + kc_) * 512 + loff); \
    } while (0)

    bf16x8 bA[8], bB[8];
    LOADH(bA, phase, 0);
    LOADH(bB, phase, 1);

    for (int ct = 0; ct < KCODES / 128; ++ct) {
        const int ctp = (ct + phase) & 31;
        const int ctn = (ctp + 1) & 31;      // next iter's tile (wraps: dead loads)
        f32x4 acc0[4], acc1[4];
        #pragma unroll
        for (int i = 0; i < 4; ++i) {
            acc0[i] = (f32x4){0.f, 0.f, 0.f, 0.f};
            acc1[i] = (f32x4){0.f, 0.f, 0.f, 0.f};
        }

        // Next-tile frag-group bases for the rolling refill.
        const int gA = ctn * 8 + w4 * 2 + 0;
        const int gB = ctn * 8 + w4 * 2 + 1;

        #pragma unroll
        for (int kc = 0; kc < 8; ++kc) {
            const bf16x8 a2k = *(const bf16x8*)(Asw + (size_t)(((rh * 4 + 2) * 8 + kc) * 64 + lane) * 8);
            const bf16x8 a3k = *(const bf16x8*)(Asw + (size_t)(((rh * 4 + 3) * 8 + kc) * 64 + lane) * 8);
            acc0[0] = __builtin_amdgcn_mfma_f32_16x16x32_bf16(ah[0][kc], bA[kc], acc0[0], 0, 0, 0);
            acc1[0] = __builtin_amdgcn_mfma_f32_16x16x32_bf16(ah[0][kc], bB[kc], acc1[0], 0, 0, 0);
            acc0[1] = __builtin_amdgcn_mfma_f32_16x16x32_bf16(ah[1][kc], bA[kc], acc0[1], 0, 0, 0);
            acc1[1] = __builtin_amdgcn_mfma_f32_16x16x32_bf16(ah[1][kc], bB[kc], acc1[1], 0, 0, 0);
            acc0[2] = __builtin_amdgcn_mfma_f32_16x16x32_bf16(a2k, bA[kc], acc0[2], 0, 0, 0);
            acc1[2] = __builtin_amdgcn_mfma_f32_16x16x32_bf16(a2k, bB[kc], acc1[2], 0, 0, 0);
            acc0[3] = __builtin_amdgcn_mfma_f32_16x16x32_bf16(a3k, bA[kc], acc0[3], 0, 0, 0);
            acc1[3] = __builtin_amdgcn_mfma_f32_16x16x32_bf16(a3k, bB[kc], acc1[3], 0, 0, 0);
            // Rolling refill: bA[kc]/bB[kc] are dead after the MFMAs above.
            bA[kc] = *(const bf16x8*)(Bsw + (size_t)(gA * 8 + kc) * 512 + loff);
            bB[kc] = *(const bf16x8*)(Bsw + (size_t)(gB * 8 + kc) * 512 + loff);
            // Pin VMEM issue points only; ALU/VALU/SALU/MFMA/DS free to cross.
            __builtin_amdgcn_sched_barrier(0x38F);
        }

        // key = qdist<<12 | code; top-3 insert = min + med3 + med3 (identical result).
        {
            const unsigned code = (unsigned)(ctp * 128 + w4 * 32 + lanem);
            #pragma unroll
            for (int i = 0; i < 4; ++i)
                #pragma unroll
                for (int r = 0; r < 4; ++r) {
                    const int s = i * 4 + r;
                    const float dist = fmaf(acc0[i][r], -2.0f * QSCALE, QBIAS * QSCALE);
                    const unsigned k = ((unsigned)dist << 12) | code;
                    const unsigned nb1 = min(b1[s], k);
                    const unsigned nb2 = med3u(b1[s], b2[s], k);
                    const unsigned nb3 = med3u(b2[s], b3[s], k);
                    b1[s] = nb1; b2[s] = nb2; b3[s] = nb3;
                }
        }
        {
            const unsigned code = (unsigned)(ctp * 128 + w4 * 32 + 16 + lanem);
            #pragma unroll
            for (int i = 0; i < 4; ++i)
                #pragma unroll
                for (int r = 0; r < 4; ++r) {
                    const int s = i * 4 + r;
                    const float dist = fmaf(acc1[i][r], -2.0f * QSCALE, QBIAS * QSCALE);
                    const unsigned k = ((unsigned)dist << 12) | code;
                    const unsigned nb1 = min(b1[s], k);
                    const unsigned nb2 = med3u(b1[s], b2[s], k);
                    const unsigned nb3 = med3u(b2[s], b3[s], k);
                    b1[s] = nb1; b2[s] = nb2; b3[s] = nb3;
                }
        }
    }
#undef LOADH

    __syncthreads();   // Asw dead from here; keys region reuses the same LDS.

    // Merge via LDS. Column src = w4*16 + lanem (0..63); rows rh*64 + 0..63.
    {
        const int src = w4 * 16 + lanem;
        #pragma unroll
        for (int i = 0; i < 4; ++i)
            #pragma unroll
            for (int r = 0; r < 4; ++r) {
                const int s = i * 4 + r;
                const int rr = rh * 64 + i * 16 + laneq * 4 + r;   // row within block
                keys[rr * 193 + src * 3 + 0] = b1[s];
                keys[rr * 193 + src * 3 + 1] = b2[s];
                keys[rr * 193 + src * 3 + 2] = b3[s];
            }
    }
    __syncthreads();
    if (tid < SROWS) {
        const int base = tid * 193;
        unsigned kmin = 0xFFFFFFFFu;
        for (int t = 0; t < 192; ++t) kmin = min(kmin, keys[base + t]);
        const unsigned thr = (((kmin >> 12) + EPSQ) << 12) | 0xFFFu;
        int cand[MAXC]; int nc = 0; int ovf = 0;
        for (int L = 0; L < 64; ++L) {
            const unsigned v0 = keys[base + L * 3 + 0];
            if (v0 <= thr) {
                if (nc < MAXC) cand[nc] = (int)(v0 & 0xFFFu);
                ++nc;
                const unsigned v1 = keys[base + L * 3 + 1];
                if (v1 <= thr) {
                    if (nc < MAXC) cand[nc] = (int)(v1 & 0xFFFu);
                    ++nc;
                    const unsigned v2 = keys[base + L * 3 + 2];
                    if (v2 <= thr) {      // column's 4th-best unknown -> conservative
                        if (nc < MAXC) cand[nc] = (int)(v2 & 0xFFFu);
                        ++nc;
                        ovf = 1;
                    }
                }
            }
        }
        const int row = rb + tid;
        const int bi = (int)(kmin & 0xFFFu);
        widx[tid] = bi;
        out[OUT_IDX + (size_t)row] = (float)bi;
        if (ovf || nc > MAXC) {
            const int op = atomicAdd(ovfcount, 1);
            if (op < OVFCAP) ovflist[op] = row;
        } else if (nc >= 2) {
            // Block-local candfix list (LDS): [rowLocal, cnt, codes[0..nc)]
            const int pos = atomicAdd(bcnt, 1);
            int* e = candL + pos * 10;
            e[0] = tid; e[1] = nc;
            for (int q = 0; q < nc; ++q) e[2 + q] = cand[q];
        }
    }
    __syncthreads();

    // Gather z_q, write z_q_st = x + (z_q - x), accumulate loss partial. 128 rows.
    // (Uses the ORIGINAL kmin index; candfix corrections below apply deltas,
    //  preserving the exact addend set of the R6..R16 scheme.)
    float lsum = 0.0f;
    const int dv = (tid & 63) * 4;
    const int rs = tid >> 6;
    const float* xblk = x + (size_t)rb * DIMD;
    float* oblk = out + (size_t)rb * DIMD;
    for (int p = 0; p < 16; ++p) {
        const int row = p * 8 + rs;
        const int wi = widx[row];
        float4 xv = *(const float4*)(xblk + (size_t)row * DIMD + dv);
        float4 cv = *(const float4*)(cb + (size_t)wi * DIMD + dv);
        const float d0 = cv.x - xv.x, d1 = cv.y - xv.y, d2 = cv.z - xv.z, d3 = cv.w - xv.w;
        float4 o;
        o.x = xv.x + d0; o.y = xv.y + d1; o.z = xv.z + d2; o.w = xv.w + d3;
        *(float4*)(oblk + (size_t)row * DIMD + dv) = o;
        lsum += d0 * d0 + d1 * d1 + d2 * d2 + d3 * d3;
    }
    #pragma unroll
    for (int off = 32; off > 0; off >>= 1) lsum += __shfl_down(lsum, off, 64);
    if ((tid & 63) == 0) wpart[tid >> 6] = lsum;
    __syncthreads();
    if (tid == 0) {
        float t = 0.0f;
        #pragma unroll
        for (int i = 0; i < 8; ++i) t += wpart[i];
        atomicAdd(loss_acc, t);
    }
    __syncthreads();   // gather writes complete before corrections

    // Fused candfix [R5..R8-proven math, verbatim]: np-bin metric over <=8
    // candidates, (dq,idx)-lex first-min; one wave per flagged row.
    {
        const int items = bcnt[0];
        for (int it = wv; it < items; it += 8) {
            const int* e = candL + it * 10;
            const int r = e[0];
            const int cnt = e[1];
            const int row = rb + r;
            const float4 xv = *(const float4*)(x + (size_t)row * DIMD + lane * 4);
            double zs = (double)xv.x * xv.x + (double)xv.y * xv.y
                      + (double)xv.z * xv.z + (double)xv.w * xv.w;
            #pragma unroll
            for (int off = 32; off > 0; off >>= 1) zs += __shfl_xor(zs, off, 64);
            const float Zf = (float)zs;   // grid-aligned z_sq (translation-invariance)
            float bq = 3.4e38f; int bi = 0x7fffffff;
            for (int q = 0; q < cnt; ++q) {
                const int c = e[2 + q];
                const float4 cv = *(const float4*)(cb + (size_t)c * DIMD + lane * 4);
                double dp = (double)xv.x * cv.x + (double)xv.y * cv.y
                          + (double)xv.z * cv.z + (double)xv.w * cv.w;
                #pragma unroll
                for (int off = 32; off > 0; off >>= 1) dp += __shfl_xor(dp, off, 64);
                const float wvv = (float)(2.0 * dp);
                const float dq = Zf - wvv;            // fp32 subtract = np's bin
                if (dq < bq || (dq == bq && c < bi)) { bq = dq; bi = c; }
            }
            const int oldi = widx[r];                 // == (int)out[OUT_IDX+row]
            if (bi != oldi) {
                const float4 cn = *(const float4*)(cb + (size_t)bi * DIMD + lane * 4);
                const float4 co = *(const float4*)(cb + (size_t)oldi * DIMD + lane * 4);
                float4 o; float ls = 0.0f;
                { const float dn = cn.x - xv.x, dd = co.x - xv.x; o.x = xv.x + dn; ls += dn*dn - dd*dd; }
                { const float dn = cn.y - xv.y, dd = co.y - xv.y; o.y = xv.y + dn; ls += dn*dn - dd*dd; }
                { const float dn = cn.z - xv.z, dd = co.z - xv.z; o.z = xv.z + dn; ls += dn*dn - dd*dd; }
                { const float dn = cn.w - xv.w, dd = co.w - xv.w; o.w = xv.w + dn; ls += dn*dn - dd*dd; }
                *(float4*)(out + (size_t)row * DIMD + lane * 4) = o;
                #pragma unroll
                for (int off = 32; off > 0; off >>= 1) ls += __shfl_xor(ls, off, 64);
                if (lane == 0) {
                    atomicAdd(loss_acc, ls);
                    out[OUT_IDX + (size_t)row] = (float)bi;
                }
            }
        }
    }
}

// Ovf full-rescan (expected ~0 items) + fused finalize (last-block ticket).
__global__ __launch_bounds__(256) void vq_ovffin_kernel(
        const float* __restrict__ x, const float* __restrict__ cb,
        float* __restrict__ out, float* __restrict__ loss_acc,
        const int* __restrict__ ovfcount, const int* __restrict__ ovflist,
        int* __restrict__ done) {
    __shared__ double xd[DIMD];
    __shared__ double zred[256];
    __shared__ float  rdq[256];
    __shared__ int    ri[256];
    __shared__ float  lred[256];
    const int tid = threadIdx.x;
    int count = ovfcount[0];
    if (count > OVFCAP) count = OVFCAP;
    for (int item = blockIdx.x; item < count; item += gridDim.x) {
        const int row = ovflist[item];
        const double xv0 = (double)x[(size_t)row * DIMD + tid];
        xd[tid] = xv0;
        zred[tid] = xv0 * xv0;
        __syncthreads();
        for (int st = 128; st > 0; st >>= 1) {
            if (tid < st) zred[tid] += zred[tid + st];
            __syncthreads();
        }
        const float Zf = (float)zred[0];
        float bq = 3.4e38f; int bi = 0x7fffffff;
        for (int q = 0; q < 16; ++q) {
            const int c = q * 256 + tid;
            const float* cr = cb + (size_t)c * DIMD;
            double s0 = 0.0, s1 = 0.0, s2 = 0.0, s3 = 0.0;
            #pragma unroll 4
            for (int d = 0; d < DIMD; d += 16) {
                float4 c0 = *(const float4*)(cr + d);
                float4 c1 = *(const float4*)(cr + d + 4);
                float4 c2 = *(const float4*)(cr + d + 8);
                float4 c3 = *(const float4*)(cr + d + 12);
                s0 += xd[d + 0] * (double)c0.x + xd[d + 1] * (double)c0.y
                    + xd[d + 2] * (double)c0.z + xd[d + 3] * (double)c0.w;
                s1 += xd[d + 4] * (double)c1.x + xd[d + 5] * (double)c1.y
                    + xd[d + 6] * (double)c1.z + xd[d + 7] * (double)c1.w;
                s2 += xd[d + 8] * (double)c2.x + xd[d + 9] * (double)c2.y
                    + xd[d +10] * (double)c2.z + xd[d +11] * (double)c2.w;
                s3 += xd[d +12] * (double)c3.x + xd[d +13] * (double)c3.y
                    + xd[d +14] * (double)c3.z + xd[d +15] * (double)c3.w;
            }
            const double s = (s0 + s1) + (s2 + s3);
            const float wv = (float)(2.0 * s);
            const float dq = Zf - wv;
            if (dq < bq || (dq == bq && c < bi)) { bq = dq; bi = c; }
        }
        rdq[tid] = bq; ri[tid] = bi;
        __syncthreads();
        for (int st = 128; st > 0; st >>= 1) {
            if (tid < st) {
                const float oq = rdq[tid + st]; const int oi = ri[tid + st];
                if (oq < rdq[tid] || (oq == rdq[tid] && oi < ri[tid])) {
                    rdq[tid] = oq; ri[tid] = oi;
                }
            }
            __syncthreads();
        }
        const int newi = ri[0];
        const int oldi = (int)out[OUT_IDX + (size_t)row];
        if (newi != oldi) {
            const float xv = x[(size_t)row * DIMD + tid];
            const float co = cb[(size_t)oldi * DIMD + tid];
            const float cn = cb[(size_t)newi * DIMD + tid];
            const float dold = co - xv, dnew = cn - xv;
            out[(size_t)row * DIMD + tid] = xv + dnew;
            lred[tid] = dnew * dnew - dold * dold;
        } else {
            lred[tid] = 0.0f;
        }
        __syncthreads();
        for (int st = 128; st > 0; st >>= 1) {
            if (tid < st) lred[tid] += lred[tid + st];
            __syncthreads();
        }
        if (tid == 0 && newi != oldi) {
            atomicAdd(loss_acc, lred[0]);
            out[OUT_IDX + (size_t)row] = (float)newi;
        }
        __syncthreads();
    }
    // Fused finalize (last-block ticket).
    if (tid == 0) {
        __threadfence();                                   // publish this block's adds
        const int t = atomicAdd(done, 1);
        if (t == (int)gridDim.x - 1) {
            __threadfence();                               // acquire all blocks' adds
            out[OUT_LOSS] = 1.25f * (loss_acc[0] / 8388608.0f);
        }
    }
}

// Standalone ovf kernel kept for the fallback fp32 path.
__global__ __launch_bounds__(256) void vq_ovf_kernel(
        const float* __restrict__ x, const float* __restrict__ cb,
        float* __restrict__ out, float* __restrict__ loss_acc,
        const int* __restrict__ ovfcount, const int* __restrict__ ovflist) {
    __shared__ double xd[DIMD];
    __shared__ double zred[256];
    __shared__ float  rdq[256];
    __shared__ int    ri[256];
    __shared__ float  lred[256];
    const int tid = threadIdx.x;
    int count = ovfcount[0];
    if (count > OVFCAP) count = OVFCAP;
    for (int item = blockIdx.x; item < count; item += gridDim.x) {
        const int row = ovflist[item];
        const double xv0 = (double)x[(size_t)row * DIMD + tid];
        xd[tid] = xv0;
        zred[tid] = xv0 * xv0;
        __syncthreads();
        for (int st = 128; st > 0; st >>= 1) {
            if (tid < st) zred[tid] += zred[tid + st];
            __syncthreads();
        }
        const float Zf = (float)zred[0];
        float bq = 3.4e38f; int bi = 0x7fffffff;
        for (int q = 0; q < 16; ++q) {
            const int c = q * 256 + tid;
            const float* cr = cb + (size_t)c * DIMD;
            double s0 = 0.0, s1 = 0.0, s2 = 0.0, s3 = 0.0;
            #pragma unroll 4
            for (int d = 0; d < DIMD; d += 16) {
                float4 c0 = *(const float4*)(cr + d);
                float4 c1 = *(const float4*)(cr + d + 4);
                float4 c2 = *(const float4*)(cr + d + 8);
                float4 c3 = *(const float4*)(cr + d + 12);
                s0 += xd[d + 0] * (double)c0.x + xd[d + 1] * (double)c0.y
                    + xd[d + 2] * (double)c0.z + xd[d + 3] * (double)c0.w;
                s1 += xd[d + 4] * (double)c1.x + xd[d + 5] * (double)c1.y
                    + xd[d + 6] * (double)c1.z + xd[d + 7] * (double)c1.w;
                s2 += xd[d + 8] * (double)c2.x + xd[d + 9] * (double)c2.y
                    + xd[d +10] * (double)c2.z + xd[d +11] * (double)c2.w;
                s3 += xd[d +12] * (double)c3.x + xd[d +13] * (double)c3.y
                    + xd[d +14] * (double)c3.z + xd[d +15] * (double)c3.w;
            }
            const double s = (s0 + s1) + (s2 + s3);
            const float wv = (float)(2.0 * s);
            const float dq = Zf - wv;
            if (dq < bq || (dq == bq && c < bi)) { bq = dq; bi = c; }
        }
        rdq[tid] = bq; ri[tid] = bi;
        __syncthreads();
        for (int st = 128; st > 0; st >>= 1) {
            if (tid < st) {
                const float oq = rdq[tid + st]; const int oi = ri[tid + st];
                if (oq < rdq[tid] || (oq == rdq[tid] && oi < ri[tid])) {
                    rdq[tid] = oq; ri[tid] = oi;
                }
            }
            __syncthreads();
        }
        const int newi = ri[0];
        const int oldi = (int)out[OUT_IDX + (size_t)row];
        if (newi != oldi) {
            const float xv = x[(size_t)row * DIMD + tid];
            const float co = cb[(size_t)oldi * DIMD + tid];
            const float cn = cb[(size_t)newi * DIMD + tid];
            const float dold = co - xv, dnew = cn - xv;
            out[(size_t)row * DIMD + tid] = xv + dnew;
            lred[tid] = dnew * dnew - dold * dold;
        } else {
            lred[tid] = 0.0f;
        }
        __syncthreads();
        for (int st = 128; st > 0; st >>= 1) {
            if (tid < st) lred[tid] += lred[tid + st];
            __syncthreads();
        }
        if (tid == 0 && newi != oldi) {
            atomicAdd(loss_acc, lred[0]);
            out[OUT_IDX + (size_t)row] = (float)newi;
        }
        __syncthreads();
    }
}

__global__ void finalize_kernel(const float* __restrict__ loss_acc, float* __restrict__ out) {
    if (threadIdx.x == 0 && blockIdx.x == 0)
        out[OUT_LOSS] = 1.25f * (loss_acc[0] / 8388608.0f);
}

// ===== fallback fp32 path (R3-proven) for small ws_size =====
#define MT 128
#define DK 32
#define LSTR 130
#define FLAG_EPS_F32 3.6e-5f
__global__ __launch_bounds__(256) void vq_main_fp32_kernel(const float* __restrict__ x,
                                                           const float* __restrict__ cb,
                                                           float* __restrict__ out,
                                                           float* __restrict__ loss_acc,
                                                           int* __restrict__ wcount,
                                                           int* __restrict__ wlist,
                                                           int wcap) {
    __shared__ float As[DK * LSTR];
    __shared__ float Bs[DK * LSTR];
    __shared__ float red_d[MT * 17];
    __shared__ float red_2[MT * 17];
    __shared__ int   red_i[MT * 17];
    __shared__ int   widx[MT];
    __shared__ float wpart[4];
    const int tid = threadIdx.x;
    const int tx = tid & 15;
    const int ty = tid >> 4;
    const float* xblk = x + (size_t)blockIdx.x * MT * DIMD;
    float b1[8], b2[8]; int i1[8];
    #pragma unroll
    for (int i = 0; i < 8; ++i) { b1[i] = 3.4e38f; b2[i] = 3.4e38f; i1[i] = 0; }
    const int sr = tid >> 3;
    const int sd = (tid & 7) * 4;
    for (int kt = 0; kt < KCODES; kt += 128) {
        float acc[8][8];
        #pragma unroll
        for (int i = 0; i < 8; ++i)
            #pragma unroll
            for (int j = 0; j < 8; ++j) acc[i][j] = 0.0f;
        const float* bblk = cb + (size_t)kt * DIMD;
        for (int dc = 0; dc < DIMD; dc += DK) {
            __syncthreads();
            #pragma unroll
            for (int p = 0; p < 4; ++p) {
                const int r = p * 32 + sr;
                float4 va = *(const float4*)(xblk + (size_t)r * DIMD + dc + sd);
                float4 vb = *(const float4*)(bblk + (size_t)r * DIMD + dc + sd);
                As[(sd + 0) * LSTR + r] = va.x; As[(sd + 1) * LSTR + r] = va.y;
                As[(sd + 2) * LSTR + r] = va.z; As[(sd + 3) * LSTR + r] = va.w;
                Bs[(sd + 0) * LSTR + r] = vb.x; Bs[(sd + 1) * LSTR + r] = vb.y;
                Bs[(sd + 2) * LSTR + r] = vb.z; Bs[(sd + 3) * LSTR + r] = vb.w;
            }
            __syncthreads();
            #pragma unroll 4
            for (int d = 0; d < DK; ++d) {
                const float2* ap = (const float2*)&As[d * LSTR + ty * 8];
                const float2* bp = (const float2*)&Bs[d * LSTR + tx * 8];
                float2 a0 = ap[0], a1 = ap[1], a2 = ap[2], a3 = ap[3];
                float2 c0 = bp[0], c1 = bp[1], c2 = bp[2], c3 = bp[3];
                float a[8] = {a0.x, a0.y, a1.x, a1.y, a2.x, a2.y, a3.x, a3.y};
                float b[8] = {c0.x, c0.y, c1.x, c1.y, c2.x, c2.y, c3.x, c3.y};
                #pragma unroll
                for (int i = 0; i < 8; ++i)
                    #pragma unroll
                    for (int j = 0; j < 8; ++j)
                        acc[i][j] += a[i] * b[j];
            }
        }
        #pragma unroll
        for (int j = 0; j < 8; ++j) {
            const int code = kt + tx * 8 + j;
            #pragma unroll
            for (int i = 0; i < 8; ++i) {
                const float dist = -(acc[i][j] + acc[i][j]);
                if (dist < b1[i]) { b2[i] = b1[i]; b1[i] = dist; i1[i] = code; }
                else if (dist < b2[i]) b2[i] = dist;
            }
        }
    }
    __syncthreads();
    #pragma unroll
    for (int i = 0; i < 8; ++i) {
        red_d[(ty * 8 + i) * 17 + tx] = b1[i];
        red_2[(ty * 8 + i) * 17 + tx] = b2[i];
        red_i[(ty * 8 + i) * 17 + tx] = i1[i];
    }
    __syncthreads();
    if (tid < MT) {
        float bd = red_d[tid * 17];
        float s2 = red_2[tid * 17];
        int   bi = red_i[tid * 17];
        #pragma unroll
        for (int t = 1; t < 16; ++t) {
            const float d1 = red_d[tid * 17 + t];
            const float d2 = red_2[tid * 17 + t];
            const int   ii = red_i[tid * 17 + t];
            if (d1 < bd || (d1 == bd && ii < bi)) { s2 = fminf(bd, d2); bd = d1; bi = ii; }
            else s2 = fminf(s2, d1);
        }
        const int row = blockIdx.x * MT + tid;
        widx[tid] = bi;
        out[OUT_IDX + (size_t)row] = (float)bi;
        if (s2 - bd <= FLAG_EPS_F32) {
            const int pos = atomicAdd(wcount, 1);
            if (pos < wcap) wlist[pos] = row;
        }
    }
    __syncthreads();
    float lsum = 0.0f;
    const int dv = (tid & 63) * 4;
    const int rs = tid >> 6;
    float* oblk = out + (size_t)blockIdx.x * MT * DIMD;
    for (int p = 0; p < 32; ++p) {
        const int row = p * 4 + rs;
        const int wi = widx[row];
        float4 xv = *(const float4*)(xblk + (size_t)row * DIMD + dv);
        float4 cv = *(const float4*)(cb + (size_t)wi * DIMD + dv);
        const float d0 = cv.x - xv.x, d1 = cv.y - xv.y, d2 = cv.z - xv.z, d3 = cv.w - xv.w;
        float4 o;
        o.x = xv.x + d0; o.y = xv.y + d1; o.z = xv.z + d2; o.w = xv.w + d3;
        *(float4*)(oblk + (size_t)row * DIMD + dv) = o;
        lsum += d0 * d0 + d1 * d1 + d2 * d2 + d3 * d3;
    }
    #pragma unroll
    for (int off = 32; off > 0; off >>= 1) lsum += __shfl_down(lsum, off, 64);
    if ((tid & 63) == 0) wpart[tid >> 6] = lsum;
    __syncthreads();
    if (tid == 0) atomicAdd(loss_acc, wpart[0] + wpart[1] + wpart[2] + wpart[3]);
}

extern "C" void kernel_launch(void* const* d_in, const int* in_sizes, int n_in,
                              void* d_out, int out_size, void* d_ws, size_t ws_size,
                              hipStream_t stream) {
    const float* x  = (const float*)d_in[0];
    const float* cb = (const float*)d_in[1];
    float* out = (float*)d_out;
    float* loss_acc = (float*)d_ws;
    int*   wcount   = (int*)((char*)d_ws + 32);
    int*   ovfcount = (int*)((char*)d_ws + 36);
    int*   done     = (int*)((char*)d_ws + 40);
    int*   ovflist  = (int*)((char*)d_ws + WS_OVF);

    if (ws_size >= (size_t)WS_END) {
        unsigned short* Bsw = (unsigned short*)((char*)d_ws + WS_BSW);
        convertB_kernel<<<512, 256, 0, stream>>>(cb, Bsw, loss_acc, wcount, ovfcount, done);
        vq_screen_kernel<<<256, 512, 0, stream>>>(Bsw, x, cb, out, loss_acc,
                                                  ovfcount, ovflist);
        vq_ovffin_kernel<<<256, 256, 0, stream>>>(x, cb, out, loss_acc,
                                                  ovfcount, ovflist, done);
    } else {
        init_kernel<<<1, 64, 0, stream>>>(loss_acc, wcount, ovfcount);
        int* wlist = (int*)((char*)d_ws + WS_CLIST);
        int wcap = 0;
        if (ws_size > WS_CLIST + sizeof(int)) {
            size_t c = (ws_size - WS_CLIST) / sizeof(int);
            wcap = (int)(c > 32768 ? 32768 : c);
        }
        vq_main_fp32_kernel<<<256, 256, 0, stream>>>(x, cb, out, loss_acc,
                                                     wcount, wlist, wcap);
        vq_ovf_kernel<<<512, 256, 0, stream>>>(x, cb, out, loss_acc, wcount, wlist);
        finalize_kernel<<<1, 1, 0, stream>>>(loss_acc, out);
    }
}